// Round 14
// baseline (39.612 us; speedup 1.0000x reference)
//
#include <hip/hip_runtime.h>

#define N_TOK 2048
#define HQ_ 16
#define HKV_ 4
#define D_ 128
#define NUM_SLOTS_ 131072
#define SEQ_ 512
#define NSEG_ 4
#define KVS (HKV_ * D_)

typedef __attribute__((ext_vector_type(8))) short bf16x8;
typedef __attribute__((ext_vector_type(4))) float f32x4;
typedef __attribute__((ext_vector_type(4))) short s16x4;

__device__ __forceinline__ unsigned cvt_pk(float lo, float hi) {
  unsigned r;
  asm("v_cvt_pk_bf16_f32 %0, %1, %2" : "=v"(r) : "v"(lo), "v"(hi));
  return r;
}
union bfu { bf16x8 v; unsigned u[4]; };

// Prep, fully parallel (2048 blocks) — r8-proven, unchanged:
//  blocks [0,1024): k_bf [seg][kvh][tok][D] bf16 (coalesced)
//  blocks [1024,2048): vt [seg][kvh][D][tok] bf16 via LDS transpose
__global__ __launch_bounds__(256) void prep_kernel(
    const float* __restrict__ k, const float* __restrict__ v,
    const float* __restrict__ k_cache, const float* __restrict__ v_cache,
    const int* __restrict__ slot_mapping,
    short* __restrict__ k_bf, short* __restrict__ vt) {
  __shared__ short tile[16][64];
  int b = blockIdx.x;
  if (b < 1024) {
    int e = (b * 256 + (int)threadIdx.x) * 4;   // element index into [N][HKV][D]
    int n = e >> 9;
    int s = slot_mapping[n];
    bool valid = (s >= 0) && (s < NUM_SLOTS_);
    int cs = s < 0 ? 0 : (s >= NUM_SLOTS_ ? NUM_SLOTS_ - 1 : s);
    const float* src = valid ? (k + e)
                             : (k_cache + (size_t)cs * KVS + (e & (KVS - 1)));
    f32x4 a = *(const f32x4*)src;
    int seg = n >> 9, tok = n & (SEQ_ - 1);
    int h = (e >> 7) & 3, d = e & 127;
    unsigned* dst = (unsigned*)(k_bf + ((size_t)((seg * HKV_ + h) * SEQ_ + tok)) * D_ + d);
    dst[0] = cvt_pk(a[0], a[1]);
    dst[1] = cvt_pk(a[2], a[3]);
  } else {
    int bb = b - 1024;                  // [ch][seg][h][dblk]
    int dblk = bb & 7, h = (bb >> 3) & 3, seg = (bb >> 5) & 3, ch = (bb >> 7) & 7;
    int d0 = dblk * 16;
    const int tid = (int)threadIdx.x;
    int tok_l = tid >> 2, dq = tid & 3;
    int n = seg * SEQ_ + ch * 64 + tok_l;
    int s = slot_mapping[n];
    bool valid = (s >= 0) && (s < NUM_SLOTS_);
    int cs = s < 0 ? 0 : (s >= NUM_SLOTS_ ? NUM_SLOTS_ - 1 : s);
    const float* src = (valid ? v + (size_t)n * KVS : v_cache + (size_t)cs * KVS)
                       + h * D_ + d0 + dq * 4;
    f32x4 x = *(const f32x4*)src;
#pragma unroll
    for (int j = 0; j < 4; ++j) tile[dq * 4 + j][tok_l] = (short)cvt_pk(x[j], x[j]);
    __syncthreads();
    int d_l = tid >> 4, tq = tid & 15;
    s16x4 o = *(const s16x4*)&tile[d_l][tq * 4];
    short* dst = vt + ((size_t)((seg * HKV_ + h) * D_ + d0 + d_l)) * SEQ_ + ch * 64 + tq * 4;
    *(s16x4*)dst = o;
  }
}

// r10/r13 (measured best, 38.7us): 512 blocks x 4 waves, q-tile pair (15-j, j)
// -> exactly 17 key-block units/block, split-K-4, fixed-M softmax, XCD
// mapping. NEW (T5): s_setprio(1) around MFMA clusters — waves here are
// barrier-free and phase-diverse, the regime where setprio paid +4-7% (m191).
// r11/r12 lessons kept: no extra waves (spill), no K prefetch regs (TLP).
__global__ __launch_bounds__(256) void attn_kernel(
    const float* __restrict__ q, const short* __restrict__ k_bf,
    const short* __restrict__ vt, float* __restrict__ out) {
  __shared__ float sm_o[3][2][8][64][4];   // 48 KB: A and B partials
  __shared__ float sm_l[3][2][64];
  const int tid = (int)threadIdx.x;
  const int wave = tid >> 6;
  const int lane = tid & 63;
  const int col = lane & 15;
  const int grp = lane >> 4;
  const int p = (int)blockIdx.x;        // 0..511
  const int xcd = p & 7;
  const int local = p >> 3;             // 0..63
  const int g = xcd * 2 + (local >> 5); // 0..15 = (seg,kvh)
  const int h2 = (local >> 3) & 3;
  const int j = local & 7;
  const int seg = g >> 2;
  const int kvh = g & 3;
  const int head = kvh * 4 + h2;
  const int segbase = seg * SEQ_;
  const float MLOG = 11.5415603f;       // 8 * log2(e)
  const short* ksegb = k_bf + (size_t)(seg * HKV_ + kvh) * SEQ_ * D_ + (size_t)col * D_ + grp * 8;
  const short* vseg = vt + ((size_t)((seg * HKV_ + kvh) * D_ + col)) * SEQ_ + grp * 8;
  const int srcA = col + ((grp & 1) << 5);
  const int srcB = srcA + 16;
  const bool lo2 = grp < 2;

#pragma unroll 1
  for (int ti = 0; ti < 2; ++ti) {
    const int qt32 = ti ? j : (15 - j); // pair: (16-j) + (j+1) = 17 units
    const int q0 = qt32 << 5;

    bf16x8 qfA[4], qfB[4];
    {
      const float sc = 0.12751742f;     // log2(e)/sqrt(128)
      const float* qpA = q + ((size_t)((segbase + q0 + col) * HQ_ + head)) * D_ + grp * 8;
      const float* qpB = qpA + (size_t)16 * HQ_ * D_;
#pragma unroll
      for (int t = 0; t < 4; ++t) {
        f32x4 a = *(const f32x4*)(qpA + t * 32);
        f32x4 bb = *(const f32x4*)(qpA + t * 32 + 4);
        bfu f;
        f.u[0] = cvt_pk(a[0] * sc, a[1] * sc);
        f.u[1] = cvt_pk(a[2] * sc, a[3] * sc);
        f.u[2] = cvt_pk(bb[0] * sc, bb[1] * sc);
        f.u[3] = cvt_pk(bb[2] * sc, bb[3] * sc);
        qfA[t] = f.v;
        a = *(const f32x4*)(qpB + t * 32);
        bb = *(const f32x4*)(qpB + t * 32 + 4);
        f.u[0] = cvt_pk(a[0] * sc, a[1] * sc);
        f.u[1] = cvt_pk(a[2] * sc, a[3] * sc);
        f.u[2] = cvt_pk(bb[0] * sc, bb[1] * sc);
        f.u[3] = cvt_pk(bb[2] * sc, bb[3] * sc);
        qfB[t] = f.v;
      }
    }

    f32x4 oA[8], oB[8];
#pragma unroll
    for (int t = 0; t < 8; ++t) { oA[t] = (f32x4){0,0,0,0}; oB[t] = (f32x4){0,0,0,0}; }
    float lA = 0.f, lB = 0.f;
    const int nfull = q0 >> 5;

    for (int blk = wave; blk < nfull; blk += 4) {
      const int k0 = blk << 5;
      const short* kp = ksegb + (size_t)k0 * D_;
      f32x4 sA0 = {0,0,0,0}, sA1 = {0,0,0,0}, sB0 = {0,0,0,0}, sB1 = {0,0,0,0};
      __builtin_amdgcn_s_setprio(1);
#pragma unroll
      for (int t = 0; t < 4; ++t) {
        bf16x8 kf0 = *(const bf16x8*)(kp + t * 32);
        bf16x8 kf1 = *(const bf16x8*)(kp + 16 * D_ + t * 32);
        sA0 = __builtin_amdgcn_mfma_f32_16x16x32_bf16(kf0, qfA[t], sA0, 0, 0, 0);
        sA1 = __builtin_amdgcn_mfma_f32_16x16x32_bf16(kf1, qfA[t], sA1, 0, 0, 0);
        sB0 = __builtin_amdgcn_mfma_f32_16x16x32_bf16(kf0, qfB[t], sB0, 0, 0, 0);
        sB1 = __builtin_amdgcn_mfma_f32_16x16x32_bf16(kf1, qfB[t], sB1, 0, 0, 0);
      }
      __builtin_amdgcn_s_setprio(0);
#pragma unroll
      for (int r = 0; r < 4; ++r) {
        sA0[r] = __builtin_amdgcn_exp2f(sA0[r] - MLOG);
        sA1[r] = __builtin_amdgcn_exp2f(sA1[r] - MLOG);
        sB0[r] = __builtin_amdgcn_exp2f(sB0[r] - MLOG);
        sB1[r] = __builtin_amdgcn_exp2f(sB1[r] - MLOG);
        lA += sA0[r] + sA1[r];
        lB += sB0[r] + sB1[r];
      }
      bfu pfA, pfB;
      {
        unsigned u0 = cvt_pk(sA0[0], sA0[1]), u1 = cvt_pk(sA0[2], sA0[3]);
        unsigned u2 = cvt_pk(sA1[0], sA1[1]), u3 = cvt_pk(sA1[2], sA1[3]);
        int a0 = __shfl((int)u0, srcA, 64), a1 = __shfl((int)u1, srcA, 64);
        int a2 = __shfl((int)u2, srcA, 64), a3 = __shfl((int)u3, srcA, 64);
        int b0 = __shfl((int)u0, srcB, 64), b1 = __shfl((int)u1, srcB, 64);
        int b2 = __shfl((int)u2, srcB, 64), b3 = __shfl((int)u3, srcB, 64);
        pfA.u[0] = lo2 ? a0 : a2; pfA.u[1] = lo2 ? a1 : a3;
        pfA.u[2] = lo2 ? b0 : b2; pfA.u[3] = lo2 ? b1 : b3;
        u0 = cvt_pk(sB0[0], sB0[1]); u1 = cvt_pk(sB0[2], sB0[3]);
        u2 = cvt_pk(sB1[0], sB1[1]); u3 = cvt_pk(sB1[2], sB1[3]);
        a0 = __shfl((int)u0, srcA, 64); a1 = __shfl((int)u1, srcA, 64);
        a2 = __shfl((int)u2, srcA, 64); a3 = __shfl((int)u3, srcA, 64);
        b0 = __shfl((int)u0, srcB, 64); b1 = __shfl((int)u1, srcB, 64);
        b2 = __shfl((int)u2, srcB, 64); b3 = __shfl((int)u3, srcB, 64);
        pfB.u[0] = lo2 ? a0 : a2; pfB.u[1] = lo2 ? a1 : a3;
        pfB.u[2] = lo2 ? b0 : b2; pfB.u[3] = lo2 ? b1 : b3;
      }
      const short* vp = vseg + k0;
      __builtin_amdgcn_s_setprio(1);
#pragma unroll
      for (int t = 0; t < 8; ++t) {
        bf16x8 vf = *(const bf16x8*)(vp + (size_t)(t * 16) * SEQ_);
        oA[t] = __builtin_amdgcn_mfma_f32_16x16x32_bf16(vf, pfA.v, oA[t], 0, 0, 0);
        oB[t] = __builtin_amdgcn_mfma_f32_16x16x32_bf16(vf, pfB.v, oB[t], 0, 0, 0);
      }
      __builtin_amdgcn_s_setprio(0);
    }

    // ---- diagonal block k0 = q0, owned by wave nfull&3 ----
    if ((nfull & 3) == wave) {
      const int k0 = q0;
      const short* kp = ksegb + (size_t)k0 * D_;
      f32x4 sA0 = {0,0,0,0}, sB0 = {0,0,0,0}, sB1 = {0,0,0,0};
      __builtin_amdgcn_s_setprio(1);
#pragma unroll
      for (int t = 0; t < 4; ++t) {
        bf16x8 kf0 = *(const bf16x8*)(kp + t * 32);
        bf16x8 kf1 = *(const bf16x8*)(kp + 16 * D_ + t * 32);
        sA0 = __builtin_amdgcn_mfma_f32_16x16x32_bf16(kf0, qfA[t], sA0, 0, 0, 0);
        sB0 = __builtin_amdgcn_mfma_f32_16x16x32_bf16(kf0, qfB[t], sB0, 0, 0, 0);
        sB1 = __builtin_amdgcn_mfma_f32_16x16x32_bf16(kf1, qfB[t], sB1, 0, 0, 0);
      }
      __builtin_amdgcn_s_setprio(0);
      f32x4 sA1 = {0, 0, 0, 0};  // tile-A rows vs keys q0+16..: always masked
#pragma unroll
      for (int r = 0; r < 4; ++r) {
        bool msk = (grp * 4 + r) > col;   // intra-16 triangle
        float pa0 = __builtin_amdgcn_exp2f(sA0[r] - MLOG);
        float pb1 = __builtin_amdgcn_exp2f(sB1[r] - MLOG);
        sA0[r] = msk ? 0.f : pa0;
        sB0[r] = __builtin_amdgcn_exp2f(sB0[r] - MLOG);  // fully unmasked
        sB1[r] = msk ? 0.f : pb1;
        lA += sA0[r];
        lB += sB0[r] + sB1[r];
      }
      bfu pfA, pfB;
      {
        unsigned u0 = cvt_pk(sA0[0], sA0[1]), u1 = cvt_pk(sA0[2], sA0[3]);
        unsigned u2 = cvt_pk(sA1[0], sA1[1]), u3 = cvt_pk(sA1[2], sA1[3]);
        int a0 = __shfl((int)u0, srcA, 64), a1 = __shfl((int)u1, srcA, 64);
        int a2 = __shfl((int)u2, srcA, 64), a3 = __shfl((int)u3, srcA, 64);
        int b0 = __shfl((int)u0, srcB, 64), b1 = __shfl((int)u1, srcB, 64);
        int b2 = __shfl((int)u2, srcB, 64), b3 = __shfl((int)u3, srcB, 64);
        pfA.u[0] = lo2 ? a0 : a2; pfA.u[1] = lo2 ? a1 : a3;
        pfA.u[2] = lo2 ? b0 : b2; pfA.u[3] = lo2 ? b1 : b3;
        u0 = cvt_pk(sB0[0], sB0[1]); u1 = cvt_pk(sB0[2], sB0[3]);
        u2 = cvt_pk(sB1[0], sB1[1]); u3 = cvt_pk(sB1[2], sB1[3]);
        a0 = __shfl((int)u0, srcA, 64); a1 = __shfl((int)u1, srcA, 64);
        a2 = __shfl((int)u2, srcA, 64); a3 = __shfl((int)u3, srcA, 64);
        b0 = __shfl((int)u0, srcB, 64); b1 = __shfl((int)u1, srcB, 64);
        b2 = __shfl((int)u2, srcB, 64); b3 = __shfl((int)u3, srcB, 64);
        pfB.u[0] = lo2 ? a0 : a2; pfB.u[1] = lo2 ? a1 : a3;
        pfB.u[2] = lo2 ? b0 : b2; pfB.u[3] = lo2 ? b1 : b3;
      }
      const short* vp = vseg + k0;
      __builtin_amdgcn_s_setprio(1);
#pragma unroll
      for (int t = 0; t < 8; ++t) {
        bf16x8 vf = *(const bf16x8*)(vp + (size_t)(t * 16) * SEQ_);
        oA[t] = __builtin_amdgcn_mfma_f32_16x16x32_bf16(vf, pfA.v, oA[t], 0, 0, 0);
        oB[t] = __builtin_amdgcn_mfma_f32_16x16x32_bf16(vf, pfB.v, oB[t], 0, 0, 0);
      }
      __builtin_amdgcn_s_setprio(0);
    }

    // ---- per-wave l reduce over grp ----
    lA += __shfl_xor(lA, 16); lA += __shfl_xor(lA, 32);
    lB += __shfl_xor(lB, 16); lB += __shfl_xor(lB, 32);

    // ---- single-phase split-K merge (barrier first: sm_o free across ti) ----
    __syncthreads();
    if (wave) {
#pragma unroll
      for (int t = 0; t < 8; ++t) {
        *(f32x4*)&sm_o[wave - 1][0][t][lane][0] = oA[t];
        *(f32x4*)&sm_o[wave - 1][1][t][lane][0] = oB[t];
      }
      sm_l[wave - 1][0][lane] = lA;
      sm_l[wave - 1][1][lane] = lB;
    }
    __syncthreads();
    if (!wave) {
      float ltotA = lA + sm_l[0][0][lane] + sm_l[1][0][lane] + sm_l[2][0][lane];
      float ltotB = lB + sm_l[0][1][lane] + sm_l[1][1][lane] + sm_l[2][1][lane];
      float linvA = 1.0f / ltotA;
      float linvB = 1.0f / ltotB;
      float* opA = out + ((size_t)((segbase + q0 + col) * HQ_ + head)) * D_ + grp * 4;
      float* opB = opA + (size_t)16 * HQ_ * D_;
#pragma unroll
      for (int t = 0; t < 8; ++t) {
        f32x4 rA = oA[t], rB = oB[t];
#pragma unroll
        for (int w = 0; w < 3; ++w) {
          rA += *(const f32x4*)&sm_o[w][0][t][lane][0];
          rB += *(const f32x4*)&sm_o[w][1][t][lane][0];
        }
        rA *= linvA;
        rB *= linvB;
        *(f32x4*)(opA + t * 16) = rA;
        *(f32x4*)(opB + t * 16) = rB;
      }
    }
  }
}

extern "C" void kernel_launch(void* const* d_in, const int* in_sizes, int n_in,
                              void* d_out, int out_size, void* d_ws, size_t ws_size,
                              hipStream_t stream) {
  const float* q = (const float*)d_in[0];
  const float* k = (const float*)d_in[1];
  const float* v = (const float*)d_in[2];
  const float* k_cache = (const float*)d_in[3];
  const float* v_cache = (const float*)d_in[4];
  const int* slot_mapping = (const int*)d_in[5];

  short* k_bf = (short*)d_ws;                               // 2 MB
  short* vt = k_bf + (size_t)N_TOK * HKV_ * D_;             // 2 MB

  prep_kernel<<<2048, 256, 0, stream>>>(k, v, k_cache, v_cache, slot_mapping, k_bf, vt);
  attn_kernel<<<512, 256, 0, stream>>>(q, k_bf, vt, (float*)d_out);
}

// Round 15
// 38.489 us; speedup vs baseline: 1.0292x; 1.0292x over previous
//
#include <hip/hip_runtime.h>

#define N_TOK 2048
#define HQ_ 16
#define HKV_ 4
#define D_ 128
#define NUM_SLOTS_ 131072
#define SEQ_ 512
#define NSEG_ 4
#define KVS (HKV_ * D_)

typedef __attribute__((ext_vector_type(8))) short bf16x8;
typedef __attribute__((ext_vector_type(4))) float f32x4;
typedef __attribute__((ext_vector_type(4))) short s16x4;

__device__ __forceinline__ unsigned cvt_pk(float lo, float hi) {
  unsigned r;
  asm("v_cvt_pk_bf16_f32 %0, %1, %2" : "=v"(r) : "v"(lo), "v"(hi));
  return r;
}
union bfu { bf16x8 v; unsigned u[4]; };

// Prep, fully parallel (2048 blocks) — r8-proven, unchanged:
//  blocks [0,1024): k_bf [seg][kvh][tok][D] bf16 (coalesced)
//  blocks [1024,2048): vt [seg][kvh][D][tok] bf16 via LDS transpose
__global__ __launch_bounds__(256) void prep_kernel(
    const float* __restrict__ k, const float* __restrict__ v,
    const float* __restrict__ k_cache, const float* __restrict__ v_cache,
    const int* __restrict__ slot_mapping,
    short* __restrict__ k_bf, short* __restrict__ vt) {
  __shared__ short tile[16][64];
  int b = blockIdx.x;
  if (b < 1024) {
    int e = (b * 256 + (int)threadIdx.x) * 4;   // element index into [N][HKV][D]
    int n = e >> 9;
    int s = slot_mapping[n];
    bool valid = (s >= 0) && (s < NUM_SLOTS_);
    int cs = s < 0 ? 0 : (s >= NUM_SLOTS_ ? NUM_SLOTS_ - 1 : s);
    const float* src = valid ? (k + e)
                             : (k_cache + (size_t)cs * KVS + (e & (KVS - 1)));
    f32x4 a = *(const f32x4*)src;
    int seg = n >> 9, tok = n & (SEQ_ - 1);
    int h = (e >> 7) & 3, d = e & 127;
    unsigned* dst = (unsigned*)(k_bf + ((size_t)((seg * HKV_ + h) * SEQ_ + tok)) * D_ + d);
    dst[0] = cvt_pk(a[0], a[1]);
    dst[1] = cvt_pk(a[2], a[3]);
  } else {
    int bb = b - 1024;                  // [ch][seg][h][dblk]
    int dblk = bb & 7, h = (bb >> 3) & 3, seg = (bb >> 5) & 3, ch = (bb >> 7) & 7;
    int d0 = dblk * 16;
    const int tid = (int)threadIdx.x;
    int tok_l = tid >> 2, dq = tid & 3;
    int n = seg * SEQ_ + ch * 64 + tok_l;
    int s = slot_mapping[n];
    bool valid = (s >= 0) && (s < NUM_SLOTS_);
    int cs = s < 0 ? 0 : (s >= NUM_SLOTS_ ? NUM_SLOTS_ - 1 : s);
    const float* src = (valid ? v + (size_t)n * KVS : v_cache + (size_t)cs * KVS)
                       + h * D_ + d0 + dq * 4;
    f32x4 x = *(const f32x4*)src;
#pragma unroll
    for (int j = 0; j < 4; ++j) tile[dq * 4 + j][tok_l] = (short)cvt_pk(x[j], x[j]);
    __syncthreads();
    int d_l = tid >> 4, tq = tid & 15;
    s16x4 o = *(const s16x4*)&tile[d_l][tq * 4];
    short* dst = vt + ((size_t)((seg * HKV_ + h) * D_ + d0 + d_l)) * SEQ_ + ch * 64 + tq * 4;
    *(s16x4*)dst = o;
  }
}

// r10/r13 (measured best, 38.7us, reproduced twice): 512 blocks x 4 waves,
// q-tile pair (15-j, j) -> exactly 17 key-block units/block (perfect
// balance), split-K-4, fixed-M softmax, XCD mapping (2 (seg,kvh) slices
// per XCD L2). Probed and rejected: coop fusion (breaks capture, r9),
// 8 waves (VGPR spill, r11), K reg-dbuf (TLP loss, r12), shuffle-free P
// (neutral, r7), setprio (neutral, r14). This config balances TLP vs VGPR.
__global__ __launch_bounds__(256) void attn_kernel(
    const float* __restrict__ q, const short* __restrict__ k_bf,
    const short* __restrict__ vt, float* __restrict__ out) {
  __shared__ float sm_o[3][2][8][64][4];   // 48 KB: A and B partials
  __shared__ float sm_l[3][2][64];
  const int tid = (int)threadIdx.x;
  const int wave = tid >> 6;
  const int lane = tid & 63;
  const int col = lane & 15;
  const int grp = lane >> 4;
  const int p = (int)blockIdx.x;        // 0..511
  const int xcd = p & 7;
  const int local = p >> 3;             // 0..63
  const int g = xcd * 2 + (local >> 5); // 0..15 = (seg,kvh)
  const int h2 = (local >> 3) & 3;
  const int j = local & 7;
  const int seg = g >> 2;
  const int kvh = g & 3;
  const int head = kvh * 4 + h2;
  const int segbase = seg * SEQ_;
  const float MLOG = 11.5415603f;       // 8 * log2(e)
  const short* ksegb = k_bf + (size_t)(seg * HKV_ + kvh) * SEQ_ * D_ + (size_t)col * D_ + grp * 8;
  const short* vseg = vt + ((size_t)((seg * HKV_ + kvh) * D_ + col)) * SEQ_ + grp * 8;
  const int srcA = col + ((grp & 1) << 5);
  const int srcB = srcA + 16;
  const bool lo2 = grp < 2;

#pragma unroll 1
  for (int ti = 0; ti < 2; ++ti) {
    const int qt32 = ti ? j : (15 - j); // pair: (16-j) + (j+1) = 17 units
    const int q0 = qt32 << 5;

    bf16x8 qfA[4], qfB[4];
    {
      const float sc = 0.12751742f;     // log2(e)/sqrt(128)
      const float* qpA = q + ((size_t)((segbase + q0 + col) * HQ_ + head)) * D_ + grp * 8;
      const float* qpB = qpA + (size_t)16 * HQ_ * D_;
#pragma unroll
      for (int t = 0; t < 4; ++t) {
        f32x4 a = *(const f32x4*)(qpA + t * 32);
        f32x4 bb = *(const f32x4*)(qpA + t * 32 + 4);
        bfu f;
        f.u[0] = cvt_pk(a[0] * sc, a[1] * sc);
        f.u[1] = cvt_pk(a[2] * sc, a[3] * sc);
        f.u[2] = cvt_pk(bb[0] * sc, bb[1] * sc);
        f.u[3] = cvt_pk(bb[2] * sc, bb[3] * sc);
        qfA[t] = f.v;
        a = *(const f32x4*)(qpB + t * 32);
        bb = *(const f32x4*)(qpB + t * 32 + 4);
        f.u[0] = cvt_pk(a[0] * sc, a[1] * sc);
        f.u[1] = cvt_pk(a[2] * sc, a[3] * sc);
        f.u[2] = cvt_pk(bb[0] * sc, bb[1] * sc);
        f.u[3] = cvt_pk(bb[2] * sc, bb[3] * sc);
        qfB[t] = f.v;
      }
    }

    f32x4 oA[8], oB[8];
#pragma unroll
    for (int t = 0; t < 8; ++t) { oA[t] = (f32x4){0,0,0,0}; oB[t] = (f32x4){0,0,0,0}; }
    float lA = 0.f, lB = 0.f;
    const int nfull = q0 >> 5;

    for (int blk = wave; blk < nfull; blk += 4) {
      const int k0 = blk << 5;
      const short* kp = ksegb + (size_t)k0 * D_;
      f32x4 sA0 = {0,0,0,0}, sA1 = {0,0,0,0}, sB0 = {0,0,0,0}, sB1 = {0,0,0,0};
#pragma unroll
      for (int t = 0; t < 4; ++t) {
        bf16x8 kf0 = *(const bf16x8*)(kp + t * 32);
        bf16x8 kf1 = *(const bf16x8*)(kp + 16 * D_ + t * 32);
        sA0 = __builtin_amdgcn_mfma_f32_16x16x32_bf16(kf0, qfA[t], sA0, 0, 0, 0);
        sA1 = __builtin_amdgcn_mfma_f32_16x16x32_bf16(kf1, qfA[t], sA1, 0, 0, 0);
        sB0 = __builtin_amdgcn_mfma_f32_16x16x32_bf16(kf0, qfB[t], sB0, 0, 0, 0);
        sB1 = __builtin_amdgcn_mfma_f32_16x16x32_bf16(kf1, qfB[t], sB1, 0, 0, 0);
      }
#pragma unroll
      for (int r = 0; r < 4; ++r) {
        sA0[r] = __builtin_amdgcn_exp2f(sA0[r] - MLOG);
        sA1[r] = __builtin_amdgcn_exp2f(sA1[r] - MLOG);
        sB0[r] = __builtin_amdgcn_exp2f(sB0[r] - MLOG);
        sB1[r] = __builtin_amdgcn_exp2f(sB1[r] - MLOG);
        lA += sA0[r] + sA1[r];
        lB += sB0[r] + sB1[r];
      }
      bfu pfA, pfB;
      {
        unsigned u0 = cvt_pk(sA0[0], sA0[1]), u1 = cvt_pk(sA0[2], sA0[3]);
        unsigned u2 = cvt_pk(sA1[0], sA1[1]), u3 = cvt_pk(sA1[2], sA1[3]);
        int a0 = __shfl((int)u0, srcA, 64), a1 = __shfl((int)u1, srcA, 64);
        int a2 = __shfl((int)u2, srcA, 64), a3 = __shfl((int)u3, srcA, 64);
        int b0 = __shfl((int)u0, srcB, 64), b1 = __shfl((int)u1, srcB, 64);
        int b2 = __shfl((int)u2, srcB, 64), b3 = __shfl((int)u3, srcB, 64);
        pfA.u[0] = lo2 ? a0 : a2; pfA.u[1] = lo2 ? a1 : a3;
        pfA.u[2] = lo2 ? b0 : b2; pfA.u[3] = lo2 ? b1 : b3;
        u0 = cvt_pk(sB0[0], sB0[1]); u1 = cvt_pk(sB0[2], sB0[3]);
        u2 = cvt_pk(sB1[0], sB1[1]); u3 = cvt_pk(sB1[2], sB1[3]);
        a0 = __shfl((int)u0, srcA, 64); a1 = __shfl((int)u1, srcA, 64);
        a2 = __shfl((int)u2, srcA, 64); a3 = __shfl((int)u3, srcA, 64);
        b0 = __shfl((int)u0, srcB, 64); b1 = __shfl((int)u1, srcB, 64);
        b2 = __shfl((int)u2, srcB, 64); b3 = __shfl((int)u3, srcB, 64);
        pfB.u[0] = lo2 ? a0 : a2; pfB.u[1] = lo2 ? a1 : a3;
        pfB.u[2] = lo2 ? b0 : b2; pfB.u[3] = lo2 ? b1 : b3;
      }
      const short* vp = vseg + k0;
#pragma unroll
      for (int t = 0; t < 8; ++t) {
        bf16x8 vf = *(const bf16x8*)(vp + (size_t)(t * 16) * SEQ_);
        oA[t] = __builtin_amdgcn_mfma_f32_16x16x32_bf16(vf, pfA.v, oA[t], 0, 0, 0);
        oB[t] = __builtin_amdgcn_mfma_f32_16x16x32_bf16(vf, pfB.v, oB[t], 0, 0, 0);
      }
    }

    // ---- diagonal block k0 = q0, owned by wave nfull&3 ----
    if ((nfull & 3) == wave) {
      const int k0 = q0;
      const short* kp = ksegb + (size_t)k0 * D_;
      f32x4 sA0 = {0,0,0,0}, sB0 = {0,0,0,0}, sB1 = {0,0,0,0};
#pragma unroll
      for (int t = 0; t < 4; ++t) {
        bf16x8 kf0 = *(const bf16x8*)(kp + t * 32);
        bf16x8 kf1 = *(const bf16x8*)(kp + 16 * D_ + t * 32);
        sA0 = __builtin_amdgcn_mfma_f32_16x16x32_bf16(kf0, qfA[t], sA0, 0, 0, 0);
        sB0 = __builtin_amdgcn_mfma_f32_16x16x32_bf16(kf0, qfB[t], sB0, 0, 0, 0);
        sB1 = __builtin_amdgcn_mfma_f32_16x16x32_bf16(kf1, qfB[t], sB1, 0, 0, 0);
      }
      f32x4 sA1 = {0, 0, 0, 0};  // tile-A rows vs keys q0+16..: always masked
#pragma unroll
      for (int r = 0; r < 4; ++r) {
        bool msk = (grp * 4 + r) > col;   // intra-16 triangle
        float pa0 = __builtin_amdgcn_exp2f(sA0[r] - MLOG);
        float pb1 = __builtin_amdgcn_exp2f(sB1[r] - MLOG);
        sA0[r] = msk ? 0.f : pa0;
        sB0[r] = __builtin_amdgcn_exp2f(sB0[r] - MLOG);  // fully unmasked
        sB1[r] = msk ? 0.f : pb1;
        lA += sA0[r];
        lB += sB0[r] + sB1[r];
      }
      bfu pfA, pfB;
      {
        unsigned u0 = cvt_pk(sA0[0], sA0[1]), u1 = cvt_pk(sA0[2], sA0[3]);
        unsigned u2 = cvt_pk(sA1[0], sA1[1]), u3 = cvt_pk(sA1[2], sA1[3]);
        int a0 = __shfl((int)u0, srcA, 64), a1 = __shfl((int)u1, srcA, 64);
        int a2 = __shfl((int)u2, srcA, 64), a3 = __shfl((int)u3, srcA, 64);
        int b0 = __shfl((int)u0, srcB, 64), b1 = __shfl((int)u1, srcB, 64);
        int b2 = __shfl((int)u2, srcB, 64), b3 = __shfl((int)u3, srcB, 64);
        pfA.u[0] = lo2 ? a0 : a2; pfA.u[1] = lo2 ? a1 : a3;
        pfA.u[2] = lo2 ? b0 : b2; pfA.u[3] = lo2 ? b1 : b3;
        u0 = cvt_pk(sB0[0], sB0[1]); u1 = cvt_pk(sB0[2], sB0[3]);
        u2 = cvt_pk(sB1[0], sB1[1]); u3 = cvt_pk(sB1[2], sB1[3]);
        a0 = __shfl((int)u0, srcA, 64); a1 = __shfl((int)u1, srcA, 64);
        a2 = __shfl((int)u2, srcA, 64); a3 = __shfl((int)u3, srcA, 64);
        b0 = __shfl((int)u0, srcB, 64); b1 = __shfl((int)u1, srcB, 64);
        b2 = __shfl((int)u2, srcB, 64); b3 = __shfl((int)u3, srcB, 64);
        pfB.u[0] = lo2 ? a0 : a2; pfB.u[1] = lo2 ? a1 : a3;
        pfB.u[2] = lo2 ? b0 : b2; pfB.u[3] = lo2 ? b1 : b3;
      }
      const short* vp = vseg + k0;
#pragma unroll
      for (int t = 0; t < 8; ++t) {
        bf16x8 vf = *(const bf16x8*)(vp + (size_t)(t * 16) * SEQ_);
        oA[t] = __builtin_amdgcn_mfma_f32_16x16x32_bf16(vf, pfA.v, oA[t], 0, 0, 0);
        oB[t] = __builtin_amdgcn_mfma_f32_16x16x32_bf16(vf, pfB.v, oB[t], 0, 0, 0);
      }
    }

    // ---- per-wave l reduce over grp ----
    lA += __shfl_xor(lA, 16); lA += __shfl_xor(lA, 32);
    lB += __shfl_xor(lB, 16); lB += __shfl_xor(lB, 32);

    // ---- single-phase split-K merge (barrier first: sm_o free across ti) ----
    __syncthreads();
    if (wave) {
#pragma unroll
      for (int t = 0; t < 8; ++t) {
        *(f32x4*)&sm_o[wave - 1][0][t][lane][0] = oA[t];
        *(f32x4*)&sm_o[wave - 1][1][t][lane][0] = oB[t];
      }
      sm_l[wave - 1][0][lane] = lA;
      sm_l[wave - 1][1][lane] = lB;
    }
    __syncthreads();
    if (!wave) {
      float ltotA = lA + sm_l[0][0][lane] + sm_l[1][0][lane] + sm_l[2][0][lane];
      float ltotB = lB + sm_l[0][1][lane] + sm_l[1][1][lane] + sm_l[2][1][lane];
      float linvA = 1.0f / ltotA;
      float linvB = 1.0f / ltotB;
      float* opA = out + ((size_t)((segbase + q0 + col) * HQ_ + head)) * D_ + grp * 4;
      float* opB = opA + (size_t)16 * HQ_ * D_;
#pragma unroll
      for (int t = 0; t < 8; ++t) {
        f32x4 rA = oA[t], rB = oB[t];
#pragma unroll
        for (int w = 0; w < 3; ++w) {
          rA += *(const f32x4*)&sm_o[w][0][t][lane][0];
          rB += *(const f32x4*)&sm_o[w][1][t][lane][0];
        }
        rA *= linvA;
        rB *= linvB;
        *(f32x4*)(opA + t * 16) = rA;
        *(f32x4*)(opB + t * 16) = rB;
      }
    }
  }
}

extern "C" void kernel_launch(void* const* d_in, const int* in_sizes, int n_in,
                              void* d_out, int out_size, void* d_ws, size_t ws_size,
                              hipStream_t stream) {
  const float* q = (const float*)d_in[0];
  const float* k = (const float*)d_in[1];
  const float* v = (const float*)d_in[2];
  const float* k_cache = (const float*)d_in[3];
  const float* v_cache = (const float*)d_in[4];
  const int* slot_mapping = (const int*)d_in[5];

  short* k_bf = (short*)d_ws;                               // 2 MB
  short* vt = k_bf + (size_t)N_TOK * HKV_ * D_;             // 2 MB

  prep_kernel<<<2048, 256, 0, stream>>>(k, v, k_cache, v_cache, slot_mapping, k_bf, vt);
  attn_kernel<<<512, 256, 0, stream>>>(q, k_bf, vt, (float*)d_out);
}